// Round 1
// baseline (683.548 us; speedup 1.0000x reference)
//
#include <hip/hip_runtime.h>

typedef unsigned short u16;
typedef __attribute__((ext_vector_type(8))) __bf16 bf16x8;
typedef __attribute__((ext_vector_type(4))) float f32x4;

#define T_SEQ 2048
#define NH 16
#define DH 64
#define DM 1024
#define NEGB (-10000.0f)

__device__ __forceinline__ u16 f2bf(float x) {
  union { float f; unsigned u; } c; c.f = x;
  unsigned r = c.u + 0x7fffu + ((c.u >> 16) & 1u);
  return (u16)(r >> 16);
}

__device__ __forceinline__ void async_load16(const void* g, void* l) {
  __builtin_amdgcn_global_load_lds(
      (const __attribute__((address_space(1))) unsigned int*)(g),
      (__attribute__((address_space(3))) unsigned int*)(l), 16, 0, 0);
}

// ---------------- convert fp32 -> bf16 ----------------
// xb: q,k,v each 8388608 elems; wb: Wq,Wk,Wv,Wo each 1048576 elems
__global__ __launch_bounds__(256) void convert_all(
    const float* __restrict__ q, const float* __restrict__ k, const float* __restrict__ v,
    const float* __restrict__ Wq, const float* __restrict__ Wk, const float* __restrict__ Wv,
    const float* __restrict__ Wo, u16* __restrict__ xb, u16* __restrict__ wb) {
  int blk = blockIdx.x;
  const float* src; u16* dst;
  if (blk < 12288) {
    int s = blk >> 12;
    src = (s == 0) ? q : (s == 1) ? k : v;
    dst = xb + (size_t)s * 8388608u;
    blk &= 4095;
  } else {
    int s = (blk - 12288) >> 9;
    src = (s == 0) ? Wq : (s == 1) ? Wk : (s == 2) ? Wv : Wo;
    dst = wb + (size_t)s * 1048576u;
    blk = (blk - 12288) & 511;
  }
  size_t base = (size_t)blk * 2048 + (size_t)threadIdx.x * 8;
  float4 a = *(const float4*)(src + base);
  float4 b2 = *(const float4*)(src + base + 4);
  u16 o[8] __attribute__((aligned(16)));
  o[0] = f2bf(a.x); o[1] = f2bf(a.y); o[2] = f2bf(a.z); o[3] = f2bf(a.w);
  o[4] = f2bf(b2.x); o[5] = f2bf(b2.y); o[6] = f2bf(b2.z); o[7] = f2bf(b2.w);
  *(uint4*)(dst + base) = *(const uint4*)o;
}

// ---------------- GEMM: C[M=8192,N=1024] = A[M,K=1024] * B[N,K]^T ----------------
// mode 0: fp32 flat to out[m*1024+n]
// mode 1: bf16 * scale to head layout [(b*16+h)*2048+t][dh], h=n>>6, dh=n&63
__global__ __launch_bounds__(256) void gemm_bt(const u16* __restrict__ A,
                                               const u16* __restrict__ Bw,
                                               void* __restrict__ out,
                                               int mode, float scale) {
  __shared__ char lds[32768]; // A frag-seq: [0,16384), B: [16384,32768)
  const int tid = threadIdx.x;
  const int wid = tid >> 6, lane = tid & 63;
  const int lm = lane & 15, lq = lane >> 4;
  const int m0 = blockIdx.x * 128, n0 = blockIdx.y * 128;
  const int wm = wid >> 1, wn = wid & 1;
  f32x4 acc[4][4] = {};

  for (int kt = 0; kt < 1024; kt += 64) {
    __syncthreads();
    // stage A & B tiles, fragment-sequential: pair p=(mt*2+kk), lane-contiguous 16B
    for (int i = 0; i < 4; ++i) {
      int p = wid * 4 + i;
      int mt = p >> 1, kk = p & 1;
      int col = kt + kk * 32 + lq * 8;
      const u16* ga = A + (size_t)(m0 + mt * 16 + lm) * 1024 + col;
      async_load16(ga, lds + p * 1024);
      const u16* gb = Bw + (size_t)(n0 + mt * 16 + lm) * 1024 + col;
      async_load16(gb, lds + 16384 + p * 1024);
    }
    __syncthreads();
    for (int kk = 0; kk < 2; ++kk) {
      bf16x8 af[4], bf[4];
      for (int i = 0; i < 4; ++i) {
        int mt = wm * 4 + i;
        af[i] = *(const bf16x8*)(lds + (mt * 2 + kk) * 1024 + lane * 16);
        int nt = wn * 4 + i;
        bf[i] = *(const bf16x8*)(lds + 16384 + (nt * 2 + kk) * 1024 + lane * 16);
      }
      for (int i = 0; i < 4; ++i)
        for (int j = 0; j < 4; ++j)
          acc[i][j] = __builtin_amdgcn_mfma_f32_16x16x32_bf16(af[i], bf[j], acc[i][j], 0, 0, 0);
    }
  }

  if (mode == 0) {
    float* O = (float*)out;
    for (int i = 0; i < 4; ++i) {
      int row = m0 + wm * 64 + i * 16 + lq * 4;
      for (int j = 0; j < 4; ++j) {
        int col = n0 + wn * 64 + j * 16 + lm;
        for (int r = 0; r < 4; ++r)
          O[(size_t)(row + r) * 1024 + col] = acc[i][j][r];
      }
    }
  } else {
    u16* O = (u16*)out;
    for (int i = 0; i < 4; ++i) {
      int row = m0 + wm * 64 + i * 16 + lq * 4;
      for (int j = 0; j < 4; ++j) {
        int col = n0 + wn * 64 + j * 16 + lm;
        int h = col >> 6, dh = col & 63;
        for (int r = 0; r < 4; ++r) {
          int m = row + r;
          int b = m >> 11, t = m & 2047;
          O[(((size_t)(b * 16 + h) * 2048 + t) << 6) + dh] = f2bf(acc[i][j][r] * scale);
        }
      }
    }
  }
}

// ---------------- Flash attention ----------------
// Qh/Kh/Vh: bf16 [B*H][T][64] (Q,K pre-scaled by Dh^-0.25). ctx: bf16 [B][T][1024].
__global__ __launch_bounds__(256) void attn_kernel(const u16* __restrict__ Qh,
                                                   const u16* __restrict__ Kh,
                                                   const u16* __restrict__ Vh,
                                                   const float* __restrict__ attn_mask,
                                                   const int* __restrict__ mfp,
                                                   u16* __restrict__ ctx) {
  __shared__ char kls[4096];     // K chunk, frag-seq: (st*2+kk)*1024 + lane*16
  __shared__ char vls[4096];     // V^T chunk, frag-seq: (nt*64+lane)*16
  __shared__ char pls[4][1024];  // per-wave P (16x32 bf16), A-frag order
  __shared__ float maskb[T_SEQ];

  const int tid = threadIdx.x;
  const int wid = tid >> 6, lane = tid & 63;
  const int lm = lane & 15, lq = lane >> 4;
  const int bid = blockIdx.x;
  const int qt = bid & 31, h = (bid >> 5) & 15, b = bid >> 9;
  const int q0 = qt * 64;
  const int mf = *mfp;
  const size_t bh = (size_t)(b * NH + h) * T_SEQ;
  const u16* Qbh = Qh + bh * DH;
  const u16* Kbh = Kh + bh * DH;
  const u16* Vbh = Vh + bh * DH;

  for (int i = tid; i < T_SEQ; i += 256)
    maskb[i] = (attn_mask[(size_t)b * T_SEQ + i] == 0.0f) ? NEGB : 0.0f;

  const int qw = q0 + wid * 16;
  bf16x8 qf[2];
  for (int kk = 0; kk < 2; ++kk)
    qf[kk] = *(const bf16x8*)(Qbh + (size_t)(qw + lm) * DH + kk * 32 + lq * 8);

  f32x4 acc[4] = {};
  float mprev[4], lsum[4];
  for (int r = 0; r < 4; ++r) { mprev[r] = -1e30f; lsum[r] = 0.0f; }

  const int nchunks = mf ? (q0 + 64) / 32 : T_SEQ / 32;
  for (int c = 0; c < nchunks; ++c) {
    int s0 = c * 32;
    __syncthreads();
    { // stage K chunk: wave wid handles pair (st=wid>>1, kk=wid&1)
      int st = wid >> 1, kk = wid & 1;
      const u16* g = Kbh + (size_t)(s0 + st * 16 + lm) * DH + kk * 32 + lq * 8;
      async_load16(g, kls + wid * 1024);
    }
    { // stage V^T: thread -> s=tid>>3, dh0=(tid&7)*8
      int s = tid >> 3, dh0 = (tid & 7) * 8;
      uint4 vv = *(const uint4*)(Vbh + (size_t)(s0 + s) * DH + dh0);
      const u16* vs = (const u16*)&vv;
      u16* vt = (u16*)vls;
      for (int j = 0; j < 8; ++j) {
        int dh = dh0 + j;
        vt[((dh >> 4) * 64 + (s >> 3) * 16 + (dh & 15)) * 8 + (s & 7)] = vs[j];
      }
    }
    __syncthreads();

    // scores: two 16x16 tiles
    f32x4 sc[2];
    for (int st = 0; st < 2; ++st) {
      f32x4 z = {0.0f, 0.0f, 0.0f, 0.0f};
      sc[st] = z;
      for (int kk = 0; kk < 2; ++kk) {
        bf16x8 kf = *(const bf16x8*)(kls + (st * 2 + kk) * 1024 + lane * 16);
        sc[st] = __builtin_amdgcn_mfma_f32_16x16x32_bf16(qf[kk], kf, sc[st], 0, 0, 0);
      }
    }
    // pad bias + causal mask (C layout: col=lm -> s, row=lq*4+r -> q)
    for (int st = 0; st < 2; ++st) {
      int sg = s0 + st * 16 + lm;
      float bias = maskb[sg];
      for (int r = 0; r < 4; ++r) {
        float vsc = sc[st][r] + bias;
        if (mf && (sg > qw + lq * 4 + r)) vsc = NEGB;
        sc[st][r] = vsc;
      }
    }
    // online softmax per row r
    float p0[4], p1[4];
    for (int r = 0; r < 4; ++r) {
      float mx = fmaxf(sc[0][r], sc[1][r]);
      for (int d = 1; d < 16; d <<= 1) mx = fmaxf(mx, __shfl_xor(mx, d, 64));
      float mn = fmaxf(mprev[r], mx);
      float alpha = __expf(mprev[r] - mn);
      float a0 = __expf(sc[0][r] - mn);
      float a1 = __expf(sc[1][r] - mn);
      float ps = a0 + a1;
      for (int d = 1; d < 16; d <<= 1) ps += __shfl_xor(ps, d, 64);
      lsum[r] = lsum[r] * alpha + ps;
      mprev[r] = mn;
      for (int nt = 0; nt < 4; ++nt) acc[nt][r] *= alpha;
      p0[r] = a0; p1[r] = a1;
    }
    // P -> LDS (A-frag order), wave-local round trip
    u16* pw = (u16*)pls[wid];
    for (int r = 0; r < 4; ++r) {
      int m = lq * 4 + r;
      int s_a = lm;        // tile 0 col
      int s_b = 16 + lm;   // tile 1 col
      pw[((s_a >> 3) * 16 + m) * 8 + (s_a & 7)] = f2bf(p0[r]);
      pw[((s_b >> 3) * 16 + m) * 8 + (s_b & 7)] = f2bf(p1[r]);
    }
    asm volatile("s_waitcnt lgkmcnt(0)" ::: "memory");
    bf16x8 pf = *(const bf16x8*)(pls[wid] + lane * 16);
    for (int nt = 0; nt < 4; ++nt) {
      bf16x8 vf = *(const bf16x8*)(vls + (nt * 64 + lane) * 16);
      acc[nt] = __builtin_amdgcn_mfma_f32_16x16x32_bf16(pf, vf, acc[nt], 0, 0, 0);
    }
  }

  // epilogue: ctx[b][t][h*64+dh] bf16
  for (int r = 0; r < 4; ++r) {
    int t = qw + lq * 4 + r;
    float inv = 1.0f / lsum[r];
    for (int nt = 0; nt < 4; ++nt) {
      int dh = nt * 16 + lm;
      ctx[((size_t)(b * T_SEQ + t) * DM) + h * DH + dh] = f2bf(acc[nt][r] * inv);
    }
  }
}

extern "C" void kernel_launch(void* const* d_in, const int* in_sizes, int n_in,
                              void* d_out, int out_size, void* d_ws, size_t ws_size,
                              hipStream_t stream) {
  const float* q = (const float*)d_in[0];
  const float* k = (const float*)d_in[1];
  const float* v = (const float*)d_in[2];
  const float* attn_mask = (const float*)d_in[3];
  const float* Wq = (const float*)d_in[4];
  const float* Wk = (const float*)d_in[5];
  const float* Wv = (const float*)d_in[6];
  const float* Wo = (const float*)d_in[7];
  const int* mf = (const int*)d_in[8];

  u16* ws = (u16*)d_ws;
  u16* qb  = ws;                       // bf16 x inputs [8192,1024] x3
  u16* kb  = ws + 8388608u;
  u16* vb  = ws + 2u * 8388608u;
  u16* wqb = ws + 3u * 8388608u;       // bf16 weights [1024,1024] x4
  u16* wkb = wqb + 1048576u;
  u16* wvb = wkb + 1048576u;
  u16* wob = wvb + 1048576u;
  u16* Qh  = wob + 1048576u;           // head layout [B*H, T, 64] x3
  u16* Kh  = Qh + 8388608u;
  u16* Vh  = Kh + 8388608u;
  u16* ctxb = ws;                      // alias over qb/kb (dead after projections)

  convert_all<<<14336, 256, 0, stream>>>(q, k, v, Wq, Wk, Wv, Wo, qb, wqb);

  const float qscale = 0.35355339059f; // 64^-0.25
  dim3 gg(64, 8);
  gemm_bt<<<gg, 256, 0, stream>>>(qb, wqb, Qh, 1, qscale);
  gemm_bt<<<gg, 256, 0, stream>>>(kb, wkb, Kh, 1, qscale);
  gemm_bt<<<gg, 256, 0, stream>>>(vb, wvb, Vh, 1, 1.0f);

  attn_kernel<<<2048, 256, 0, stream>>>(Qh, Kh, Vh, attn_mask, mf, ctxb);

  gemm_bt<<<gg, 256, 0, stream>>>(ctxb, wob, d_out, 0, 1.0f);
}

// Round 3
// 399.027 us; speedup vs baseline: 1.7130x; 1.7130x over previous
//
#include <hip/hip_runtime.h>

typedef unsigned short u16;
typedef __attribute__((ext_vector_type(8))) __bf16 bf16x8;
typedef __attribute__((ext_vector_type(4))) float f32x4;

#define T_SEQ 2048
#define NH 16
#define DH 64
#define DM 1024
// NEG * log2(e), masks applied in log2 domain (softmax via exp2)
#define NEG2 (-14426.95f)
// 64^-0.25 * sqrt(log2(e)) : folded so S^T comes out pre-scaled for exp2
#define QS2 (0.42466089f)

__device__ __forceinline__ u16 f2bf(float x) {
  union { float f; unsigned u; } c; c.f = x;
  unsigned r = c.u + 0x7fffu + ((c.u >> 16) & 1u);
  return (u16)(r >> 16);
}

__device__ __forceinline__ void async_load16(const void* g, void* l) {
  __builtin_amdgcn_global_load_lds(
      (const __attribute__((address_space(1))) unsigned int*)(g),
      (__attribute__((address_space(3))) unsigned int*)(l), 16, 0, 0);
}

// ---------------- convert fp32 -> bf16 ----------------
__global__ __launch_bounds__(256) void convert_all(
    const float* __restrict__ q, const float* __restrict__ k, const float* __restrict__ v,
    const float* __restrict__ Wq, const float* __restrict__ Wk, const float* __restrict__ Wv,
    const float* __restrict__ Wo, u16* __restrict__ xb, u16* __restrict__ wb) {
  int blk = blockIdx.x;
  const float* src; u16* dst;
  if (blk < 12288) {
    int s = blk >> 12;
    src = (s == 0) ? q : (s == 1) ? k : v;
    dst = xb + (size_t)s * 8388608u;
    blk &= 4095;
  } else {
    int s = (blk - 12288) >> 9;
    src = (s == 0) ? Wq : (s == 1) ? Wk : (s == 2) ? Wv : Wo;
    dst = wb + (size_t)s * 1048576u;
    blk = (blk - 12288) & 511;
  }
  size_t base = (size_t)blk * 2048 + (size_t)threadIdx.x * 8;
  float4 a = *(const float4*)(src + base);
  float4 b2 = *(const float4*)(src + base + 4);
  u16 o[8] __attribute__((aligned(16)));
  o[0] = f2bf(a.x); o[1] = f2bf(a.y); o[2] = f2bf(a.z); o[3] = f2bf(a.w);
  o[4] = f2bf(b2.x); o[5] = f2bf(b2.y); o[6] = f2bf(b2.z); o[7] = f2bf(b2.w);
  *(uint4*)(dst + base) = *(const uint4*)o;
}

// ---------------- fused QKV projection GEMM ----------------
// which = n0>>10 selects INPUT activation (q/k/v contiguous at A + which*8M),
// weight (Wq/Wk/Wv), and output.
// Q/K -> head layout [bh][t][dh] bf16, scaled by QS2.
// V   -> transposed head layout VT [bh][dh][t] bf16 (conflict-free attn staging).
__global__ __launch_bounds__(256) void gemm_qkv(const u16* __restrict__ A,
                                                const u16* __restrict__ Wqb,
                                                const u16* __restrict__ Wkb,
                                                const u16* __restrict__ Wvb,
                                                u16* __restrict__ Qh, u16* __restrict__ Kh,
                                                u16* __restrict__ VTh) {
  __shared__ char lds[32768];
  const int tid = threadIdx.x;
  const int wid = tid >> 6, lane = tid & 63;
  const int lm = lane & 15, lq = lane >> 4;
  const int m0 = blockIdx.x * 128;
  const int n0 = blockIdx.y * 128;
  const int which = n0 >> 10;
  const int n0l = n0 & 1023;
  const u16* As = A + (size_t)which * 8388608u;  // q / k / v activations
  const u16* Bw = (which == 0) ? Wqb : (which == 1) ? Wkb : Wvb;
  const int wm = wid >> 1, wn = wid & 1;
  f32x4 acc[4][4] = {};

  for (int kt = 0; kt < 1024; kt += 64) {
    __syncthreads();
    for (int i = 0; i < 4; ++i) {
      int p = wid * 4 + i;
      int mt = p >> 1, kk = p & 1;
      int col = kt + kk * 32 + lq * 8;
      async_load16(As + (size_t)(m0 + mt * 16 + lm) * 1024 + col, lds + p * 1024);
      async_load16(Bw + (size_t)(n0l + mt * 16 + lm) * 1024 + col, lds + 16384 + p * 1024);
    }
    __syncthreads();
    for (int kk = 0; kk < 2; ++kk) {
      bf16x8 af[4], bf[4];
      for (int i = 0; i < 4; ++i) {
        af[i] = *(const bf16x8*)(lds + ((wm * 4 + i) * 2 + kk) * 1024 + lane * 16);
        bf[i] = *(const bf16x8*)(lds + 16384 + ((wn * 4 + i) * 2 + kk) * 1024 + lane * 16);
      }
      for (int i = 0; i < 4; ++i)
        for (int j = 0; j < 4; ++j)
          acc[i][j] = __builtin_amdgcn_mfma_f32_16x16x32_bf16(af[i], bf[j], acc[i][j], 0, 0, 0);
    }
  }

  if (which < 2) {
    u16* O = which ? Kh : Qh;
    for (int i = 0; i < 4; ++i) {
      int row = m0 + wm * 64 + i * 16 + lq * 4;
      for (int j = 0; j < 4; ++j) {
        int nc = n0l + wn * 64 + j * 16 + lm;
        int h = nc >> 6, dh = nc & 63;
        for (int r = 0; r < 4; ++r) {
          int m = row + r;
          int b = m >> 11, t = m & 2047;
          O[(((size_t)(b * NH + h) * T_SEQ + t) << 6) + dh] = f2bf(acc[i][j][r] * QS2);
        }
      }
    }
  } else {
    for (int i = 0; i < 4; ++i) {
      int row = m0 + wm * 64 + i * 16 + lq * 4;
      int b = row >> 11, t0 = row & 2047;  // 4 consecutive t, same b
      for (int j = 0; j < 4; ++j) {
        int nc = n0l + wn * 64 + j * 16 + lm;
        int h = nc >> 6, dh = nc & 63;
        u16 tmp[4] __attribute__((aligned(8)));
        for (int r = 0; r < 4; ++r) tmp[r] = f2bf(acc[i][j][r]);
        *(uint2*)(VTh + (((size_t)(b * NH + h) * DH + dh) << 11) + t0) = *(const uint2*)tmp;
      }
    }
  }
}

// ---------------- output projection GEMM (fp32 out) ----------------
__global__ __launch_bounds__(256) void gemm_out(const u16* __restrict__ A,
                                                const u16* __restrict__ Bw,
                                                float* __restrict__ O) {
  __shared__ char lds[32768];
  const int tid = threadIdx.x;
  const int wid = tid >> 6, lane = tid & 63;
  const int lm = lane & 15, lq = lane >> 4;
  const int m0 = blockIdx.x * 128, n0 = blockIdx.y * 128;
  const int wm = wid >> 1, wn = wid & 1;
  f32x4 acc[4][4] = {};

  for (int kt = 0; kt < 1024; kt += 64) {
    __syncthreads();
    for (int i = 0; i < 4; ++i) {
      int p = wid * 4 + i;
      int mt = p >> 1, kk = p & 1;
      int col = kt + kk * 32 + lq * 8;
      async_load16(A + (size_t)(m0 + mt * 16 + lm) * 1024 + col, lds + p * 1024);
      async_load16(Bw + (size_t)(n0 + mt * 16 + lm) * 1024 + col, lds + 16384 + p * 1024);
    }
    __syncthreads();
    for (int kk = 0; kk < 2; ++kk) {
      bf16x8 af[4], bf[4];
      for (int i = 0; i < 4; ++i) {
        af[i] = *(const bf16x8*)(lds + ((wm * 4 + i) * 2 + kk) * 1024 + lane * 16);
        bf[i] = *(const bf16x8*)(lds + 16384 + ((wn * 4 + i) * 2 + kk) * 1024 + lane * 16);
      }
      for (int i = 0; i < 4; ++i)
        for (int j = 0; j < 4; ++j)
          acc[i][j] = __builtin_amdgcn_mfma_f32_16x16x32_bf16(af[i], bf[j], acc[i][j], 0, 0, 0);
    }
  }
  for (int i = 0; i < 4; ++i) {
    int row = m0 + wm * 64 + i * 16 + lq * 4;
    for (int j = 0; j < 4; ++j) {
      int col = n0 + wn * 64 + j * 16 + lm;
      for (int r = 0; r < 4; ++r)
        O[(size_t)(row + r) * 1024 + col] = acc[i][j][r];
    }
  }
}

// ---------------- Flash attention (S^T formulation) ----------------
// Qh/Kh: bf16 [bh][t][64] pre-scaled by QS2 (so S^T = log2e * scaled scores).
// VTh: bf16 [bh][dh][t]. ctx out: bf16 [b][t][1024].
// Block: (b,h, pair) -> q-tiles qt=pr and 31-pr (uniform causal work).
// Wave wid owns q rows [q0+wid*16, +16). s-chunk = 64.
__global__ __launch_bounds__(256) void attn_kernel(const u16* __restrict__ Qh,
                                                   const u16* __restrict__ Kh,
                                                   const u16* __restrict__ VTh,
                                                   const float* __restrict__ attn_mask,
                                                   const int* __restrict__ mfp,
                                                   u16* __restrict__ ctx) {
  __shared__ char kls[8192];      // K cells (st,kk): frag-seq, lane*16
  __shared__ char vls[8192];      // V^T cells (nt,kk): frag-seq, lane*16
  __shared__ char pls[4][2048];   // per-wave P (16q x 64s) in A-frag order
  __shared__ float maskb[T_SEQ];  // pad bias in log2 domain

  const int tid = threadIdx.x;
  const int wid = tid >> 6, lane = tid & 63;
  const int lm = lane & 15, lq = lane >> 4;
  const int bid = blockIdx.x;
  const int pr = bid & 15, h = (bid >> 4) & 15, b = bid >> 8;
  const int mf = *mfp;
  const size_t bh = (size_t)(b * NH + h);
  const u16* Qbh = Qh + bh * T_SEQ * DH;
  const u16* Kbh = Kh + bh * T_SEQ * DH;
  const u16* VTbh = VTh + bh * DH * T_SEQ;

  for (int i = tid; i < T_SEQ; i += 256)
    maskb[i] = (attn_mask[(size_t)b * T_SEQ + i] == 0.0f) ? NEG2 : 0.0f;

  for (int half = 0; half < 2; ++half) {
    const int qt = half ? (31 - pr) : pr;
    const int q0 = qt * 64;
    const int qw = q0 + wid * 16;
    // Q as B-operand: lane needs Q[q=qw+lm][k=kk*32+lq*8+j]
    bf16x8 qf[2];
    qf[0] = *(const bf16x8*)(Qbh + (size_t)(qw + lm) * DH + lq * 8);
    qf[1] = *(const bf16x8*)(Qbh + (size_t)(qw + lm) * DH + 32 + lq * 8);

    f32x4 acc[4] = {};               // O: row=q_loc(lq*4+r), col=dh(nt*16+lm)
    float mprev = -1e30f, lsum = 0.f; // state for q = qw+lm (replicated over lq)

    const int nch = mf ? (qt + 1) : 32;
    for (int c = 0; c < nch; ++c) {
      const int s0 = c * 64;
      __syncthreads();
      // stage K cells (st=wid, kk=0/1) and V cells (nt=wid, kk=0/1)
      async_load16(Kbh + (size_t)(s0 + wid * 16 + lm) * DH + lq * 8, kls + (wid * 2 + 0) * 1024);
      async_load16(Kbh + (size_t)(s0 + wid * 16 + lm) * DH + 32 + lq * 8, kls + (wid * 2 + 1) * 1024);
      async_load16(VTbh + (size_t)(wid * 16 + lm) * T_SEQ + s0 + lq * 8, vls + (wid * 2 + 0) * 1024);
      async_load16(VTbh + (size_t)(wid * 16 + lm) * T_SEQ + s0 + 32 + lq * 8, vls + (wid * 2 + 1) * 1024);
      __syncthreads();

      // S^T tiles: A=K (m=s), B=Q (n=q). sc[st]: row s_loc=lq*4+r, col q=qw+lm
      f32x4 sc[4];
      for (int st = 0; st < 4; ++st) {
        f32x4 z = {0.f, 0.f, 0.f, 0.f};
        sc[st] = z;
        for (int kk = 0; kk < 2; ++kk) {
          bf16x8 kf = *(const bf16x8*)(kls + ((st * 2 + kk) * 64 + lane) * 16);
          sc[st] = __builtin_amdgcn_mfma_f32_16x16x32_bf16(kf, qf[kk], sc[st], 0, 0, 0);
        }
      }
      // pad bias (per-s) — broadcast LDS reads
      for (int st = 0; st < 4; ++st) {
        f32x4 mb = *(const f32x4*)(maskb + s0 + st * 16 + lq * 4);
        for (int r = 0; r < 4; ++r) sc[st][r] += mb[r];
      }
      // causal: only diagonal-overlapping chunks need the compare
      if (mf && (s0 + 64 > qw)) {
        int qg = qw + lm;
        for (int st = 0; st < 4; ++st)
          for (int r = 0; r < 4; ++r)
            if (s0 + st * 16 + lq * 4 + r > qg) sc[st][r] = NEG2;
      }
      // online softmax over s (rows + lq-groups): 2 shfls per reduction
      float mx = fmaxf(fmaxf(sc[0][0], sc[0][1]), fmaxf(sc[0][2], sc[0][3]));
      for (int st = 1; st < 4; ++st) {
        float t2 = fmaxf(fmaxf(sc[st][0], sc[st][1]), fmaxf(sc[st][2], sc[st][3]));
        mx = fmaxf(mx, t2);
      }
      mx = fmaxf(mx, __shfl_xor(mx, 16));
      mx = fmaxf(mx, __shfl_xor(mx, 32));
      float mn = fmaxf(mprev, mx);
      float alpha = exp2f(mprev - mn);
      float ps = 0.f;
      for (int st = 0; st < 4; ++st)
        for (int r = 0; r < 4; ++r) {
          float p = exp2f(sc[st][r] - mn);
          sc[st][r] = p;
          ps += p;
        }
      ps += __shfl_xor(ps, 16);
      ps += __shfl_xor(ps, 32);
      lsum = lsum * alpha + ps;
      mprev = mn;
      // rescale O: alpha lives at lane lm=q; O rows need q=lq*4+r
      for (int r = 0; r < 4; ++r) {
        float ar = __shfl(alpha, lq * 4 + r);
        for (int nt = 0; nt < 4; ++nt) acc[nt][r] *= ar;
      }
      // P -> per-wave LDS in A-frag order (packed u32 writes)
      {
        char* pw = pls[wid];
        for (int st = 0; st < 4; ++st) {
          int kk = st >> 1;
          int lqp = (st & 1) * 2 + (lq >> 1);
          int base = kk * 1024 + (lqp * 16 + lm) * 16 + (lq & 1) * 8;
          unsigned v0 = (unsigned)f2bf(sc[st][0]) | ((unsigned)f2bf(sc[st][1]) << 16);
          unsigned v1 = (unsigned)f2bf(sc[st][2]) | ((unsigned)f2bf(sc[st][3]) << 16);
          *(unsigned*)(pw + base) = v0;
          *(unsigned*)(pw + base + 4) = v1;
        }
      }
      asm volatile("s_waitcnt lgkmcnt(0)" ::: "memory");
      for (int kk = 0; kk < 2; ++kk) {
        bf16x8 pf = *(const bf16x8*)(pls[wid] + kk * 1024 + lane * 16);
        for (int nt = 0; nt < 4; ++nt) {
          bf16x8 vf = *(const bf16x8*)(vls + ((nt * 2 + kk) * 64 + lane) * 16);
          acc[nt] = __builtin_amdgcn_mfma_f32_16x16x32_bf16(pf, vf, acc[nt], 0, 0, 0);
        }
      }
    }
    // epilogue: ctx[b][t][h*64+dh]
    float inv = 1.0f / lsum;
    for (int r = 0; r < 4; ++r) {
      float ir = __shfl(inv, lq * 4 + r);
      int t = qw + lq * 4 + r;
      for (int nt = 0; nt < 4; ++nt)
        ctx[((size_t)(b * T_SEQ + t) * DM) + h * DH + nt * 16 + lm] = f2bf(acc[nt][r] * ir);
    }
  }
}

extern "C" void kernel_launch(void* const* d_in, const int* in_sizes, int n_in,
                              void* d_out, int out_size, void* d_ws, size_t ws_size,
                              hipStream_t stream) {
  const float* q = (const float*)d_in[0];
  const float* k = (const float*)d_in[1];
  const float* v = (const float*)d_in[2];
  const float* attn_mask = (const float*)d_in[3];
  const float* Wq = (const float*)d_in[4];
  const float* Wk = (const float*)d_in[5];
  const float* Wv = (const float*)d_in[6];
  const float* Wo = (const float*)d_in[7];
  const int* mf = (const int*)d_in[8];

  u16* ws = (u16*)d_ws;
  u16* qb  = ws;                      // bf16 inputs [8192,1024] x3 (q,k,v contiguous)
  u16* wqb = ws + 3u * 8388608u;      // bf16 weights x4
  u16* wkb = wqb + 1048576u;
  u16* wvb = wkb + 1048576u;
  u16* wob = wvb + 1048576u;
  u16* Qh  = wob + 1048576u;          // [bh][t][64]
  u16* Kh  = Qh + 8388608u;           // [bh][t][64]
  u16* VTh = Kh + 8388608u;           // [bh][dh][2048]
  u16* ctxb = ws;                     // alias over qb (dead after projections)

  convert_all<<<14336, 256, 0, stream>>>(q, k, v, Wq, Wk, Wv, Wo, qb, wqb);

  dim3 gq(64, 24);
  gemm_qkv<<<gq, 256, 0, stream>>>(qb, wqb, wkb, wvb, Qh, Kh, VTh);

  attn_kernel<<<1024, 256, 0, stream>>>(Qh, Kh, VTh, attn_mask, mf, ctxb);

  dim3 gg(64, 8);
  gemm_out<<<gg, 256, 0, stream>>>(ctxb, wob, (float*)d_out);
}

// Round 5
// 380.723 us; speedup vs baseline: 1.7954x; 1.0481x over previous
//
#include <hip/hip_runtime.h>

typedef unsigned short u16;
typedef __attribute__((ext_vector_type(8))) _Float16 f16x8;
typedef __attribute__((ext_vector_type(2))) __fp16 fp16v2;
typedef __attribute__((ext_vector_type(4))) float f32x4;

#define T_SEQ 2048
#define NH 16
#define DH 64
#define DM 1024
// NEG * log2(e), masks applied in log2 domain (softmax via exp2)
#define NEG2 (-14426.95f)
// 64^-0.25 * sqrt(log2(e)) : folded so S^T comes out pre-scaled for exp2
#define QS2 (0.42466089f)

__device__ __forceinline__ unsigned pk2(float a, float b) {
  union { fp16v2 v; unsigned u; } c;
  c.v = __builtin_amdgcn_cvt_pkrtz(a, b);
  return c.u;
}
__device__ __forceinline__ u16 f2h(float a) {
  union { _Float16 h; u16 u; } c; c.h = (_Float16)a; return c.u;
}

__device__ __forceinline__ void async_load16(const void* g, void* l) {
  __builtin_amdgcn_global_load_lds(
      (const __attribute__((address_space(1))) unsigned int*)(g),
      (__attribute__((address_space(3))) unsigned int*)(l), 16, 0, 0);
}

// ---------------- convert fp32 -> fp16 ----------------
__global__ __launch_bounds__(256) void convert_all(
    const float* __restrict__ q, const float* __restrict__ k, const float* __restrict__ v,
    const float* __restrict__ Wq, const float* __restrict__ Wk, const float* __restrict__ Wv,
    const float* __restrict__ Wo, u16* __restrict__ xb, u16* __restrict__ wb) {
  int blk = blockIdx.x;
  const float* src; u16* dst;
  if (blk < 12288) {
    int s = blk >> 12;
    src = (s == 0) ? q : (s == 1) ? k : v;
    dst = xb + (size_t)s * 8388608u;
    blk &= 4095;
  } else {
    int s = (blk - 12288) >> 9;
    src = (s == 0) ? Wq : (s == 1) ? Wk : (s == 2) ? Wv : Wo;
    dst = wb + (size_t)s * 1048576u;
    blk = (blk - 12288) & 511;
  }
  size_t base = (size_t)blk * 2048 + (size_t)threadIdx.x * 8;
  float4 a = *(const float4*)(src + base);
  float4 b2 = *(const float4*)(src + base + 4);
  uint4 st;
  st.x = pk2(a.x, a.y); st.y = pk2(a.z, a.w);
  st.z = pk2(b2.x, b2.y); st.w = pk2(b2.z, b2.w);
  *(uint4*)(dst + base) = st;
}

// ---------------- fused QKV projection GEMM ----------------
// which = n0>>10 selects INPUT activation (q/k/v at A+which*8M), weight, output.
// which<2 (Q/K): MFMA operands SWAPPED (A-op = weights) so acc r-dim = channel;
//   epilogue packs along r, LDS-transposes, stores [bh][t][dh] coalesced (dwordx4).
// which==2 (V): normal order, acc r-dim = t; stores VT [bh][dh][t] coalesced.
__global__ __launch_bounds__(256) void gemm_qkv(const u16* __restrict__ A,
                                                const u16* __restrict__ Wqb,
                                                const u16* __restrict__ Wkb,
                                                const u16* __restrict__ Wvb,
                                                u16* __restrict__ Qh, u16* __restrict__ Kh,
                                                u16* __restrict__ VTh) {
  __shared__ char lds[33792];  // staging [0,32768); epilogue tile 128x264B
  const int tid = threadIdx.x;
  const int wid = tid >> 6, lane = tid & 63;
  const int lm = lane & 15, lq = lane >> 4;
  const int m0 = blockIdx.x * 128;
  const int n0 = blockIdx.y * 128;
  const int which = n0 >> 10;
  const int n0l = n0 & 1023;
  const u16* As = A + (size_t)which * 8388608u;
  const u16* Bw = (which == 0) ? Wqb : (which == 1) ? Wkb : Wvb;
  const int wm = wid >> 1, wn = wid & 1;
  // rbase: LDS region feeding the MFMA A-operand (row dim), cbase: B-operand
  char* const rbase = (which < 2) ? (lds + 16384) : lds;       // W : X
  char* const cbase = (which < 2) ? lds : (lds + 16384);       // X : W
  f32x4 acc[4][4] = {};

  for (int kt = 0; kt < 1024; kt += 64) {
    __syncthreads();
    for (int i = 0; i < 4; ++i) {
      int p = wid * 4 + i;
      int mt = p >> 1, kk = p & 1;
      int col = kt + kk * 32 + lq * 8;
      async_load16(As + (size_t)(m0 + mt * 16 + lm) * 1024 + col, lds + p * 1024);
      async_load16(Bw + (size_t)(n0l + mt * 16 + lm) * 1024 + col, lds + 16384 + p * 1024);
    }
    __syncthreads();
    for (int kk = 0; kk < 2; ++kk) {
      f16x8 rf[4], cf[4];
      for (int i = 0; i < 4; ++i) {
        rf[i] = *(const f16x8*)(rbase + ((wm * 4 + i) * 2 + kk) * 1024 + lane * 16);
        cf[i] = *(const f16x8*)(cbase + ((wn * 4 + i) * 2 + kk) * 1024 + lane * 16);
      }
      for (int i = 0; i < 4; ++i)
        for (int j = 0; j < 4; ++j)
          acc[i][j] = __builtin_amdgcn_mfma_f32_16x16x32_f16(rf[i], cf[j], acc[i][j], 0, 0, 0);
    }
  }

  // epilogue: pack along r (4 consecutive in row-dim), LDS tile [coldim][rowdim]
  const float s = (which < 2) ? QS2 : 1.0f;
  __syncthreads();
  for (int i = 0; i < 4; ++i)
    for (int j = 0; j < 4; ++j) {
      uint2 pv;
      pv.x = pk2(acc[i][j][0] * s, acc[i][j][1] * s);
      pv.y = pk2(acc[i][j][2] * s, acc[i][j][3] * s);
      *(uint2*)(lds + (wn * 64 + j * 16 + lm) * 264 + (wm * 64 + i * 16 + lq * 4) * 2) = pv;
    }
  __syncthreads();

  const int b = m0 >> 11, t0 = m0 & 2047, h0 = n0l >> 6;
  if (which < 2) {
    // LDS rows = t_local (128), each 128 ch (2 heads x 64 dh)
    u16* O = which ? Kh : Qh;
    for (int p = 0; p < 8; ++p) {
      int row = p * 16 + (tid >> 4);  // t_local
      int seg = tid & 15;
      uint4 val = *(const uint4*)(lds + row * 264 + seg * 16);
      int hl = seg >> 3, dh0 = (seg & 7) * 8;
      *(uint4*)(O + (((size_t)(b * NH + h0 + hl) * T_SEQ + t0 + row) << 6) + dh0) = val;
    }
  } else {
    // LDS rows = ch_local (128), each 128 t
    for (int p = 0; p < 8; ++p) {
      int row = p * 16 + (tid >> 4);  // ch_local
      int seg = tid & 15;
      uint4 val = *(const uint4*)(lds + row * 264 + seg * 16);
      int h = h0 + (row >> 6), dh = row & 63;
      *(uint4*)(VTh + (((size_t)(b * NH + h) * DH + dh) << 11) + t0 + seg * 8) = val;
    }
  }
}

// ---------------- output projection GEMM (fp32 out) ----------------
__global__ __launch_bounds__(256) void gemm_out(const u16* __restrict__ A,
                                                const u16* __restrict__ Bw,
                                                float* __restrict__ O) {
  __shared__ char lds[32768];
  const int tid = threadIdx.x;
  const int wid = tid >> 6, lane = tid & 63;
  const int lm = lane & 15, lq = lane >> 4;
  const int m0 = blockIdx.x * 128, n0 = blockIdx.y * 128;
  const int wm = wid >> 1, wn = wid & 1;
  f32x4 acc[4][4] = {};

  for (int kt = 0; kt < 1024; kt += 64) {
    __syncthreads();
    for (int i = 0; i < 4; ++i) {
      int p = wid * 4 + i;
      int mt = p >> 1, kk = p & 1;
      int col = kt + kk * 32 + lq * 8;
      async_load16(A + (size_t)(m0 + mt * 16 + lm) * 1024 + col, lds + p * 1024);
      async_load16(Bw + (size_t)(n0 + mt * 16 + lm) * 1024 + col, lds + 16384 + p * 1024);
    }
    __syncthreads();
    for (int kk = 0; kk < 2; ++kk) {
      f16x8 af[4], bf[4];
      for (int i = 0; i < 4; ++i) {
        af[i] = *(const f16x8*)(lds + ((wm * 4 + i) * 2 + kk) * 1024 + lane * 16);
        bf[i] = *(const f16x8*)(lds + 16384 + ((wn * 4 + i) * 2 + kk) * 1024 + lane * 16);
      }
      for (int i = 0; i < 4; ++i)
        for (int j = 0; j < 4; ++j)
          acc[i][j] = __builtin_amdgcn_mfma_f32_16x16x32_f16(af[i], bf[j], acc[i][j], 0, 0, 0);
    }
  }
  for (int i = 0; i < 4; ++i) {
    int row = m0 + wm * 64 + i * 16 + lq * 4;
    for (int j = 0; j < 4; ++j) {
      int col = n0 + wn * 64 + j * 16 + lm;
      for (int r = 0; r < 4; ++r)
        O[(size_t)(row + r) * 1024 + col] = acc[i][j][r];
    }
  }
}

// ---------------- Flash attention (S^T formulation, fp16) ----------------
// Qh/Kh: f16 [bh][t][64] pre-scaled by QS2. VTh: f16 [bh][dh][t].
// ctx out: f16 [b][t][1024]. Block: (b,h,pair) -> q-tiles pr and 31-pr.
__global__ __launch_bounds__(256) void attn_kernel(const u16* __restrict__ Qh,
                                                   const u16* __restrict__ Kh,
                                                   const u16* __restrict__ VTh,
                                                   const float* __restrict__ attn_mask,
                                                   const int* __restrict__ mfp,
                                                   u16* __restrict__ ctx) {
  __shared__ char kls[8192];      // K cells (st,kk): frag-seq, lane*16
  __shared__ char vls[8192];      // V^T cells (nt,kk): frag-seq, lane*16
  __shared__ char pls[4][2048];   // per-wave P (16q x 64s) in A-frag order
  __shared__ float maskb[T_SEQ];  // pad bias in log2 domain
  __shared__ int mzf;             // 1 if any pad-mask zero for this b

  const int tid = threadIdx.x;
  const int wid = tid >> 6, lane = tid & 63;
  const int lm = lane & 15, lq = lane >> 4;
  const int bid = blockIdx.x;
  const int pr = bid & 15, h = (bid >> 4) & 15, b = bid >> 8;
  const int mf = *mfp;
  const size_t bh = (size_t)(b * NH + h);
  const u16* Qbh = Qh + bh * T_SEQ * DH;
  const u16* Kbh = Kh + bh * T_SEQ * DH;
  const u16* VTbh = VTh + bh * DH * T_SEQ;

  if (tid == 0) mzf = 0;
  __syncthreads();
  {
    int az = 0;
    for (int i = tid; i < T_SEQ; i += 256) {
      float mv = attn_mask[(size_t)b * T_SEQ + i];
      maskb[i] = (mv == 0.0f) ? NEG2 : 0.0f;
      az |= (mv == 0.0f);
    }
    if (az) mzf = 1;  // benign same-value race
  }
  __syncthreads();
  const int maskzero = mzf;

  for (int half = 0; half < 2; ++half) {
    const int qt = half ? (31 - pr) : pr;
    const int q0 = qt * 64;
    const int qw = q0 + wid * 16;
    // Q as B-operand: lane needs Q[q=qw+lm][k=kk*32+lq*8+j]
    f16x8 qf[2];
    qf[0] = *(const f16x8*)(Qbh + (size_t)(qw + lm) * DH + lq * 8);
    qf[1] = *(const f16x8*)(Qbh + (size_t)(qw + lm) * DH + 32 + lq * 8);

    f32x4 acc[4] = {};                // O: row=q_loc(lq*4+r), col=dh(nt*16+lm)
    float mprev = -1e30f, lsum = 0.f; // state for q = qw+lm (replicated over lq)

    const int nch = mf ? (qt + 1) : 32;
    for (int c = 0; c < nch; ++c) {
      const int s0 = c * 64;
      __syncthreads();
      // stage K cells (st=wid, kk=0/1) and V cells (nt=wid, kk=0/1)
      async_load16(Kbh + (size_t)(s0 + wid * 16 + lm) * DH + lq * 8, kls + (wid * 2 + 0) * 1024);
      async_load16(Kbh + (size_t)(s0 + wid * 16 + lm) * DH + 32 + lq * 8, kls + (wid * 2 + 1) * 1024);
      async_load16(VTbh + (size_t)(wid * 16 + lm) * T_SEQ + s0 + lq * 8, vls + (wid * 2 + 0) * 1024);
      async_load16(VTbh + (size_t)(wid * 16 + lm) * T_SEQ + s0 + 32 + lq * 8, vls + (wid * 2 + 1) * 1024);
      __syncthreads();

      // S^T tiles: A=K (m=s), B=Q (n=q). sc[st]: row s_loc=lq*4+r, col q=qw+lm
      f32x4 sc[4];
      for (int st = 0; st < 4; ++st) {
        f32x4 z = {0.f, 0.f, 0.f, 0.f};
        sc[st] = z;
        for (int kk = 0; kk < 2; ++kk) {
          f16x8 kf = *(const f16x8*)(kls + ((st * 2 + kk) * 64 + lane) * 16);
          sc[st] = __builtin_amdgcn_mfma_f32_16x16x32_f16(kf, qf[kk], sc[st], 0, 0, 0);
        }
      }
      // pad bias only when the mask actually has zeros (wave-uniform skip)
      if (maskzero) {
        for (int st = 0; st < 4; ++st) {
          f32x4 mb = *(const f32x4*)(maskb + s0 + st * 16 + lq * 4);
          for (int r = 0; r < 4; ++r) sc[st][r] += mb[r];
        }
      }
      // causal: only diagonal-overlapping chunks need the compare
      if (mf && (s0 + 64 > qw)) {
        int qg = qw + lm;
        for (int st = 0; st < 4; ++st)
          for (int r = 0; r < 4; ++r)
            if (s0 + st * 16 + lq * 4 + r > qg) sc[st][r] = NEG2;
      }
      // online softmax over s: chunk max, then conditional rescale
      float mx = fmaxf(fmaxf(sc[0][0], sc[0][1]), fmaxf(sc[0][2], sc[0][3]));
      for (int st = 1; st < 4; ++st) {
        float t2 = fmaxf(fmaxf(sc[st][0], sc[st][1]), fmaxf(sc[st][2], sc[st][3]));
        mx = fmaxf(mx, t2);
      }
      mx = fmaxf(mx, __shfl_xor(mx, 16));
      mx = fmaxf(mx, __shfl_xor(mx, 32));
      float mn = mprev;
      if (__ballot(mx > mprev) != 0ull) {  // wave-uniform: any row's max grew
        mn = fmaxf(mprev, mx);
        float alpha = exp2f(mprev - mn);
        for (int r = 0; r < 4; ++r) {
          float ar = __shfl(alpha, lq * 4 + r);
          for (int nt = 0; nt < 4; ++nt) acc[nt][r] *= ar;
        }
        lsum *= alpha;
        mprev = mn;
      }
      float ps = 0.f;
      for (int st = 0; st < 4; ++st)
        for (int r = 0; r < 4; ++r) {
          float p = exp2f(sc[st][r] - mn);
          sc[st][r] = p;
          ps += p;
        }
      ps += __shfl_xor(ps, 16);
      ps += __shfl_xor(ps, 32);
      lsum += ps;
      // P -> per-wave LDS in A-frag order (packed b64 writes, pkrtz)
      {
        char* pw = pls[wid];
        for (int st = 0; st < 4; ++st) {
          int kk = st >> 1;
          int lqp = (st & 1) * 2 + (lq >> 1);
          uint2 pv;
          pv.x = pk2(sc[st][0], sc[st][1]);
          pv.y = pk2(sc[st][2], sc[st][3]);
          *(uint2*)(pw + kk * 1024 + (lqp * 16 + lm) * 16 + (lq & 1) * 8) = pv;
        }
      }
      asm volatile("s_waitcnt lgkmcnt(0)" ::: "memory");
      for (int kk = 0; kk < 2; ++kk) {
        f16x8 pf = *(const f16x8*)(pls[wid] + kk * 1024 + lane * 16);
        for (int nt = 0; nt < 4; ++nt) {
          f16x8 vf = *(const f16x8*)(vls + ((nt * 2 + kk) * 64 + lane) * 16);
          acc[nt] = __builtin_amdgcn_mfma_f32_16x16x32_f16(pf, vf, acc[nt], 0, 0, 0);
        }
      }
    }
    // epilogue: ctx[b][t][h*64+dh] f16
    float inv = 1.0f / lsum;
    for (int r = 0; r < 4; ++r) {
      float ir = __shfl(inv, lq * 4 + r);
      int t = qw + lq * 4 + r;
      for (int nt = 0; nt < 4; ++nt)
        ctx[((size_t)(b * T_SEQ + t) * DM) + h * DH + nt * 16 + lm] = f2h(acc[nt][r] * ir);
    }
  }
}

extern "C" void kernel_launch(void* const* d_in, const int* in_sizes, int n_in,
                              void* d_out, int out_size, void* d_ws, size_t ws_size,
                              hipStream_t stream) {
  const float* q = (const float*)d_in[0];
  const float* k = (const float*)d_in[1];
  const float* v = (const float*)d_in[2];
  const float* attn_mask = (const float*)d_in[3];
  const float* Wq = (const float*)d_in[4];
  const float* Wk = (const float*)d_in[5];
  const float* Wv = (const float*)d_in[6];
  const float* Wo = (const float*)d_in[7];
  const int* mf = (const int*)d_in[8];

  u16* ws = (u16*)d_ws;
  u16* qb  = ws;                      // f16 inputs [8192,1024] x3 (q,k,v contiguous)
  u16* wqb = ws + 3u * 8388608u;      // f16 weights x4
  u16* wkb = wqb + 1048576u;
  u16* wvb = wkb + 1048576u;
  u16* wob = wvb + 1048576u;
  u16* Qh  = wob + 1048576u;          // [bh][t][64]
  u16* Kh  = Qh + 8388608u;           // [bh][t][64]
  u16* VTh = Kh + 8388608u;           // [bh][dh][2048]
  u16* ctxb = ws;                     // alias over qb (dead after projections)

  convert_all<<<14336, 256, 0, stream>>>(q, k, v, Wq, Wk, Wv, Wo, qb, wqb);

  dim3 gq(64, 24);
  gemm_qkv<<<gq, 256, 0, stream>>>(qb, wqb, wkb, wvb, Qh, Kh, VTh);

  attn_kernel<<<1024, 256, 0, stream>>>(Qh, Kh, VTh, attn_mask, mf, ctxb);

  dim3 gg(64, 8);
  gemm_out<<<gg, 256, 0, stream>>>(ctxb, wob, (float*)d_out);
}